// Round 5
// baseline (6873.171 us; speedup 1.0000x reference)
//
#include <hip/hip_runtime.h>
#include <math.h>

// PGJANET persistent kernel, round 5.
// 16 batch-groups x 16 col-slice WGs (512 thr). Each group's 8 batches are
// split into two independent recurrence chains A (mb0-3) / B (mb4-7),
// interleaved inside the WG so each IC exchange hop is covered by the other
// chain's compute. Exchange = self-validating 16B chunks {f0,f1,seq,0} via
// sc0 sc1 dwordx4 (transaction-atomic); A/B chunks of one producer adjacent
// (32B pair) so consumers poll both with one address.

#define B_   128
#define T_   1024
#define H_   256
#define GB   16
#define GC   16
#define MB   8
#define NS   16
#define NTHR 512
#define HPAD 264

typedef float    f32x4 __attribute__((ext_vector_type(4)));
typedef unsigned u32x4 __attribute__((ext_vector_type(4)));

__device__ __forceinline__ void sys_st_x4(unsigned* p, u32x4 v) {
  asm volatile("global_store_dwordx4 %0, %1, off sc0 sc1" :: "v"(p), "v"(v) : "memory");
}
// load a 32B pair (two adjacent 16B chunks) from the coherence point
__device__ __forceinline__ void sys_ld_pair(const unsigned* p, u32x4& a, u32x4& b) {
  asm volatile("global_load_dwordx4 %0, %2, off sc0 sc1\n\t"
               "global_load_dwordx4 %1, %2, off offset:16 sc0 sc1\n\t"
               "s_waitcnt vmcnt(0)"
               : "=&v"(a), "=&v"(b) : "v"(p) : "memory");
}

__device__ __forceinline__ float ftanh(float x) {
  x = fminf(fmaxf(x, -15.f), 15.f);
  float e = __expf(-2.f * x);
  return (1.f - e) * __builtin_amdgcn_rcpf(1.f + e);
}
__device__ __forceinline__ float fsigm(float x) {
  x = fminf(fmaxf(x, -30.f), 30.f);
  return __builtin_amdgcn_rcpf(1.f + __expf(-x));
}

__launch_bounds__(NTHR, 1)
__global__ void pgjanet_persist(
    const float* __restrict__ x,   const float* __restrict__ h0,
    const float* __restrict__ Wa,  const float* __restrict__ ba,
    const float* __restrict__ Wp1, const float* __restrict__ bp1,
    const float* __restrict__ Wp2, const float* __restrict__ bp2,
    const float* __restrict__ Wz,  const float* __restrict__ bz,
    const float* __restrict__ Wh,  const float* __restrict__ bh,
    const float* __restrict__ Wo,  const float* __restrict__ bo,
    float* __restrict__ out,        // [B*T*2] then h_n [B*H]
    unsigned* __restrict__ u_ex,    // [GB][512 pairs * 8 uints]
    unsigned* __restrict__ h_ex)    // [GB][512 pairs * 8 uints]
{
  __shared__ __align__(16) float w1t[3 * NS * 256];   // 48 KB
  __shared__ __align__(16) float w2t[2 * NS * 512];   // 64 KB
  __shared__ __align__(16) float h_lds[MB * HPAD];    // 8.25 KB
  __shared__ __align__(16) float u_lds[MB * HPAD];    // 8.25 KB
  __shared__ __align__(16) float wo_s[H_ * 2];        // 2 KB
  __shared__ __align__(16) float xin[2 * MB * 4];     // double-buffered {amp,cos,sin,0}

  const int wg   = blockIdx.x;
  const int g    = wg >> 4;
  const int gc   = wg & (GC - 1);
  const int tid  = threadIdx.x;
  const int lane = tid & 63;
  const int wave = tid >> 6;       // 0..7, owns cols {2w, 2w+1}
  const int mbl  = lane >> 4;      // 0..3 (within a half)
  const int ks   = lane & 15;      // k-slice lane (16-way)
  const int b0   = g * MB;
  const int n0   = gc * NS + wave * 2;

  // ---- one-time weight staging (transposed to [col][k]) ----
  for (int i = tid; i < 3 * NS * 256; i += NTHR) {
    int c = i >> 8, k = i & 255;
    int mat = c >> 4, n = c & 15;
    const float* W = (mat == 0) ? Wa : (mat == 1 ? Wp1 : Wp2);
    w1t[i] = W[(1 + k) * H_ + gc * NS + n];
  }
  for (int i = tid; i < 2 * NS * 512; i += NTHR) {
    int c = i >> 9, k = i & 511;
    int mat = c >> 4, n = c & 15;
    const float* W = (mat == 0) ? Wz : Wh;
    w2t[i] = W[k * H_ + gc * NS + n];
  }
  for (int i = tid; i < H_ * 2; i += NTHR) wo_s[i] = Wo[i];

  float w1r0_[6], b1_[6];
#pragma unroll
  for (int m = 0; m < 3; ++m) {
    const float* W  = (m == 0) ? Wa : (m == 1 ? Wp1 : Wp2);
    const float* bb = (m == 0) ? ba : (m == 1 ? bp1 : bp2);
#pragma unroll
    for (int cc = 0; cc < 2; ++cc) {
      w1r0_[m * 2 + cc] = W[n0 + cc];
      b1_[m * 2 + cc]   = bb[n0 + cc];
    }
  }
  float bz_[2] = { bz[n0], bz[n0 + 1] };
  float bh_[2] = { bh[n0], bh[n0 + 1] };
  const float bo0 = bo[0], bo1 = bo[1];

  // h0 -> h_lds ; x(0) -> xin[0]
  {
    int mbb = tid >> 6, kk = (tid & 63) * 4;
    *(f32x4*)(h_lds + mbb * HPAD + kk) = *(const f32x4*)(h0 + (b0 + mbb) * H_ + kk);
  }
  if (tid < MB) {
    float2 xt = *(const float2*)(x + ((b0 + tid) * T_) * 2);
    f32x4 xi; xi[0] = xt.x; xi[1] = cosf(xt.y); xi[2] = sinf(xt.y); xi[3] = 0.f;
    *(f32x4*)(xin + tid * 4) = xi;
  }
  __syncthreads();

  unsigned* u_exg = u_ex + g * 4096;    // 512 pairs * 8 uints
  unsigned* h_exg = h_ex + g * 4096;
  // producer pair index = (gc*8+wave)*4 + mbl ; chunk = pair*2 + s (s=half)
  unsigned* u_my = u_exg + (((gc * 8 + wave) * 4 + mbl) * 2) * 4;
  unsigned* h_my = h_exg + (((gc * 8 + wave) * 4 + mbl) * 2) * 4;
  // consumer: thread tid owns pair tid: mb'=tid&3, w'=(tid>>2)&7, gc'=tid>>5
  const unsigned* pu = u_exg + tid * 8;
  const unsigned* ph = h_exg + tid * 8;
  const int ccol = (tid >> 5) * 16 + ((tid >> 2) & 7) * 2;
  const int cmb  = tid & 3;

  for (int t = 0; t < T_; ++t) {
    const unsigned seq = (unsigned)(t + 1);

    f32x4 hvA[4], hvB[4];
    float acc2A[4] = {0.f, 0.f, 0.f, 0.f};
    float acc2B[4] = {0.f, 0.f, 0.f, 0.f};

    // ================= S1_A =================
#pragma unroll
    for (int kt = 0; kt < 4; ++kt)
      hvA[kt] = *(const f32x4*)(h_lds + mbl * HPAD + kt * 64 + ks * 4);
    {
      float acc[6] = {0.f, 0.f, 0.f, 0.f, 0.f, 0.f};
#pragma unroll
      for (int kt = 0; kt < 4; ++kt) {
        f32x4 h4 = hvA[kt];
#pragma unroll
        for (int m = 0; m < 3; ++m)
#pragma unroll
          for (int cc = 0; cc < 2; ++cc) {
            f32x4 w4 = *(const f32x4*)(w1t + (m * NS + wave * 2 + cc) * 256 + kt * 64 + ks * 4);
            float s = acc[m * 2 + cc];
            s = fmaf(h4[0], w4[0], s); s = fmaf(h4[1], w4[1], s);
            s = fmaf(h4[2], w4[2], s); s = fmaf(h4[3], w4[3], s);
            acc[m * 2 + cc] = s;
          }
      }
#pragma unroll
      for (int i = 0; i < 6; ++i) {
        float v = acc[i];
        v += __shfl_xor(v, 1); v += __shfl_xor(v, 2);
        v += __shfl_xor(v, 4); v += __shfl_xor(v, 8);
        acc[i] = v;
      }
      if (ks == 0) {
        f32x4 xi = *(const f32x4*)(xin + ((t & 1) * MB + mbl) * 4);
        float a0  = ftanh(acc[0] + xi[0] * w1r0_[0] + b1_[0]);
        float a1  = ftanh(acc[1] + xi[0] * w1r0_[1] + b1_[1]);
        float p10 = ftanh(acc[2] + xi[1] * w1r0_[2] + b1_[2]);
        float p11 = ftanh(acc[3] + xi[1] * w1r0_[3] + b1_[3]);
        float p20 = ftanh(acc[4] + xi[2] * w1r0_[4] + b1_[4]);
        float p21 = ftanh(acc[5] + xi[2] * w1r0_[5] + b1_[5]);
        u32x4 ch;
        ch.x = __float_as_uint(a0 * p10 * p20 * (1.f - a0) * (1.f - p10) * (1.f - p20));
        ch.y = __float_as_uint(a1 * p11 * p21 * (1.f - a1) * (1.f - p11) * (1.f - p21));
        ch.z = seq; ch.w = 0u;
        sys_st_x4(u_my, ch);
      }
    }
    // ================= S1_B =================
#pragma unroll
    for (int kt = 0; kt < 4; ++kt)
      hvB[kt] = *(const f32x4*)(h_lds + (4 + mbl) * HPAD + kt * 64 + ks * 4);
    {
      float acc[6] = {0.f, 0.f, 0.f, 0.f, 0.f, 0.f};
#pragma unroll
      for (int kt = 0; kt < 4; ++kt) {
        f32x4 h4 = hvB[kt];
#pragma unroll
        for (int m = 0; m < 3; ++m)
#pragma unroll
          for (int cc = 0; cc < 2; ++cc) {
            f32x4 w4 = *(const f32x4*)(w1t + (m * NS + wave * 2 + cc) * 256 + kt * 64 + ks * 4);
            float s = acc[m * 2 + cc];
            s = fmaf(h4[0], w4[0], s); s = fmaf(h4[1], w4[1], s);
            s = fmaf(h4[2], w4[2], s); s = fmaf(h4[3], w4[3], s);
            acc[m * 2 + cc] = s;
          }
      }
#pragma unroll
      for (int i = 0; i < 6; ++i) {
        float v = acc[i];
        v += __shfl_xor(v, 1); v += __shfl_xor(v, 2);
        v += __shfl_xor(v, 4); v += __shfl_xor(v, 8);
        acc[i] = v;
      }
      if (ks == 0) {
        f32x4 xi = *(const f32x4*)(xin + ((t & 1) * MB + 4 + mbl) * 4);
        float a0  = ftanh(acc[0] + xi[0] * w1r0_[0] + b1_[0]);
        float a1  = ftanh(acc[1] + xi[0] * w1r0_[1] + b1_[1]);
        float p10 = ftanh(acc[2] + xi[1] * w1r0_[2] + b1_[2]);
        float p11 = ftanh(acc[3] + xi[1] * w1r0_[3] + b1_[3]);
        float p20 = ftanh(acc[4] + xi[2] * w1r0_[4] + b1_[4]);
        float p21 = ftanh(acc[5] + xi[2] * w1r0_[5] + b1_[5]);
        u32x4 ch;
        ch.x = __float_as_uint(a0 * p10 * p20 * (1.f - a0) * (1.f - p10) * (1.f - p20));
        ch.y = __float_as_uint(a1 * p11 * p21 * (1.f - a1) * (1.f - p11) * (1.f - p21));
        ch.z = seq; ch.w = 0u;
        sys_st_x4(u_my + 4, ch);
      }
    }

    // ============== cover window (u-hop in flight) ==============
    if (t + 1 < T_ && tid < MB) {
      float2 xt = *(const float2*)(x + ((b0 + tid) * T_ + (t + 1)) * 2);
      f32x4 xi; xi[0] = xt.x; xi[1] = cosf(xt.y); xi[2] = sinf(xt.y); xi[3] = 0.f;
      *(f32x4*)(xin + (((t + 1) & 1) * MB + tid) * 4) = xi;
    }
    if (t > 0 && ((t - 1) & 15) == gc) {   // out[t-1] = h(t) @ Wo + bo
      f32x4 h4  = *(const f32x4*)(h_lds + wave * HPAD + lane * 4);
      f32x4 wo0 = *(const f32x4*)(wo_s + lane * 8);
      f32x4 wo1 = *(const f32x4*)(wo_s + lane * 8 + 4);
      float v0 = h4[0] * wo0[0] + h4[1] * wo0[2] + h4[2] * wo1[0] + h4[3] * wo1[2];
      float v1 = h4[0] * wo0[1] + h4[1] * wo0[3] + h4[2] * wo1[1] + h4[3] * wo1[3];
      v0 += __shfl_xor(v0, 1);  v1 += __shfl_xor(v1, 1);
      v0 += __shfl_xor(v0, 2);  v1 += __shfl_xor(v1, 2);
      v0 += __shfl_xor(v0, 4);  v1 += __shfl_xor(v1, 4);
      v0 += __shfl_xor(v0, 8);  v1 += __shfl_xor(v1, 8);
      v0 += __shfl_xor(v0, 16); v1 += __shfl_xor(v1, 16);
      v0 += __shfl_xor(v0, 32); v1 += __shfl_xor(v1, 32);
      if (lane == 0) {
        float2 o; o.x = v0 + bo0; o.y = v1 + bo1;
        *(float2*)(out + ((b0 + wave) * T_ + (t - 1)) * 2) = o;
      }
    }
    // S2 h-parts (K = 256..511)
#pragma unroll
    for (int kt = 0; kt < 4; ++kt) {
      f32x4 hA = hvA[kt], hB = hvB[kt];
#pragma unroll
      for (int m = 0; m < 2; ++m)
#pragma unroll
        for (int cc = 0; cc < 2; ++cc) {
          f32x4 w4 = *(const f32x4*)(w2t + (m * NS + wave * 2 + cc) * 512 + 256 + kt * 64 + ks * 4);
          float sa = acc2A[m * 2 + cc], sb = acc2B[m * 2 + cc];
          sa = fmaf(hA[0], w4[0], sa); sa = fmaf(hA[1], w4[1], sa);
          sa = fmaf(hA[2], w4[2], sa); sa = fmaf(hA[3], w4[3], sa);
          sb = fmaf(hB[0], w4[0], sb); sb = fmaf(hB[1], w4[1], sb);
          sb = fmaf(hB[2], w4[2], sb); sb = fmaf(hB[3], w4[3], sb);
          acc2A[m * 2 + cc] = sa; acc2B[m * 2 + cc] = sb;
        }
    }

    // ============== consume u (A & B, one pair) ==============
    {
      u32x4 A, Bc;
      for (;;) {
        sys_ld_pair(pu, A, Bc);
        if (A.z == seq && Bc.z == seq) break;
        __builtin_amdgcn_s_sleep(1);
      }
      float2 d0; d0.x = __uint_as_float(A.x);  d0.y = __uint_as_float(A.y);
      float2 d1; d1.x = __uint_as_float(Bc.x); d1.y = __uint_as_float(Bc.y);
      *(float2*)(u_lds + cmb * HPAD + ccol)       = d0;
      *(float2*)(u_lds + (cmb + 4) * HPAD + ccol) = d1;
    }
    __syncthreads();                         // u_lds ready

    // ================= S2u_A + epilogue2_A =================
#pragma unroll
    for (int kt = 0; kt < 4; ++kt) {
      f32x4 u4 = *(const f32x4*)(u_lds + mbl * HPAD + kt * 64 + ks * 4);
#pragma unroll
      for (int m = 0; m < 2; ++m)
#pragma unroll
        for (int cc = 0; cc < 2; ++cc) {
          f32x4 w4 = *(const f32x4*)(w2t + (m * NS + wave * 2 + cc) * 512 + kt * 64 + ks * 4);
          float s = acc2A[m * 2 + cc];
          s = fmaf(u4[0], w4[0], s); s = fmaf(u4[1], w4[1], s);
          s = fmaf(u4[2], w4[2], s); s = fmaf(u4[3], w4[3], s);
          acc2A[m * 2 + cc] = s;
        }
    }
#pragma unroll
    for (int i = 0; i < 4; ++i) {
      float v = acc2A[i];
      v += __shfl_xor(v, 1); v += __shfl_xor(v, 2);
      v += __shfl_xor(v, 4); v += __shfl_xor(v, 8);
      acc2A[i] = v;
    }
    if (ks == 0) {
      float z0  = fsigm(acc2A[0] + bz_[0]);
      float z1  = fsigm(acc2A[1] + bz_[1]);
      float hc0 = ftanh(acc2A[2] + bh_[0]);
      float hc1 = ftanh(acc2A[3] + bh_[1]);
      float2 hp = *(const float2*)(h_lds + mbl * HPAD + n0);
      float hn0 = z0 * hp.x + (1.f - z0) * hc0;
      float hn1 = z1 * hp.y + (1.f - z1) * hc1;
      u32x4 ch;
      ch.x = __float_as_uint(hn0); ch.y = __float_as_uint(hn1);
      ch.z = seq; ch.w = 0u;
      sys_st_x4(h_my, ch);
      if (t == T_ - 1) {
        float2 o; o.x = hn0; o.y = hn1;
        *(float2*)(out + B_ * T_ * 2 + (b0 + mbl) * H_ + n0) = o;
      }
    }
    // ================= S2u_B + epilogue2_B =================
#pragma unroll
    for (int kt = 0; kt < 4; ++kt) {
      f32x4 u4 = *(const f32x4*)(u_lds + (4 + mbl) * HPAD + kt * 64 + ks * 4);
#pragma unroll
      for (int m = 0; m < 2; ++m)
#pragma unroll
        for (int cc = 0; cc < 2; ++cc) {
          f32x4 w4 = *(const f32x4*)(w2t + (m * NS + wave * 2 + cc) * 512 + kt * 64 + ks * 4);
          float s = acc2B[m * 2 + cc];
          s = fmaf(u4[0], w4[0], s); s = fmaf(u4[1], w4[1], s);
          s = fmaf(u4[2], w4[2], s); s = fmaf(u4[3], w4[3], s);
          acc2B[m * 2 + cc] = s;
        }
    }
#pragma unroll
    for (int i = 0; i < 4; ++i) {
      float v = acc2B[i];
      v += __shfl_xor(v, 1); v += __shfl_xor(v, 2);
      v += __shfl_xor(v, 4); v += __shfl_xor(v, 8);
      acc2B[i] = v;
    }
    if (ks == 0) {
      float z0  = fsigm(acc2B[0] + bz_[0]);
      float z1  = fsigm(acc2B[1] + bz_[1]);
      float hc0 = ftanh(acc2B[2] + bh_[0]);
      float hc1 = ftanh(acc2B[3] + bh_[1]);
      float2 hp = *(const float2*)(h_lds + (4 + mbl) * HPAD + n0);
      float hn0 = z0 * hp.x + (1.f - z0) * hc0;
      float hn1 = z1 * hp.y + (1.f - z1) * hc1;
      u32x4 ch;
      ch.x = __float_as_uint(hn0); ch.y = __float_as_uint(hn1);
      ch.z = seq; ch.w = 0u;
      sys_st_x4(h_my + 4, ch);
      if (t == T_ - 1) {
        float2 o; o.x = hn0; o.y = hn1;
        *(float2*)(out + B_ * T_ * 2 + (b0 + 4 + mbl) * H_ + n0) = o;
      }
    }
    __syncthreads();   // all h_lds(hprev)/out-GEMV reads done before overwrite

    // ============== consume h(t+1) (A & B, one pair) ==============
    {
      u32x4 A, Bc;
      for (;;) {
        sys_ld_pair(ph, A, Bc);
        if (A.z == seq && Bc.z == seq) break;
        __builtin_amdgcn_s_sleep(1);
      }
      float2 d0; d0.x = __uint_as_float(A.x);  d0.y = __uint_as_float(A.y);
      float2 d1; d1.x = __uint_as_float(Bc.x); d1.y = __uint_as_float(Bc.y);
      *(float2*)(h_lds + cmb * HPAD + ccol)       = d0;
      *(float2*)(h_lds + (cmb + 4) * HPAD + ccol) = d1;
    }
    __syncthreads();                         // h(t+1) ready
  }

  // ---- tail: out[T-1] from h(T) (already in h_lds) ----
  if (gc == ((T_ - 1) & 15)) {
    f32x4 h4  = *(const f32x4*)(h_lds + wave * HPAD + lane * 4);
    f32x4 wo0 = *(const f32x4*)(wo_s + lane * 8);
    f32x4 wo1 = *(const f32x4*)(wo_s + lane * 8 + 4);
    float v0 = h4[0] * wo0[0] + h4[1] * wo0[2] + h4[2] * wo1[0] + h4[3] * wo1[2];
    float v1 = h4[0] * wo0[1] + h4[1] * wo0[3] + h4[2] * wo1[1] + h4[3] * wo1[3];
    v0 += __shfl_xor(v0, 1);  v1 += __shfl_xor(v1, 1);
    v0 += __shfl_xor(v0, 2);  v1 += __shfl_xor(v1, 2);
    v0 += __shfl_xor(v0, 4);  v1 += __shfl_xor(v1, 4);
    v0 += __shfl_xor(v0, 8);  v1 += __shfl_xor(v1, 8);
    v0 += __shfl_xor(v0, 16); v1 += __shfl_xor(v1, 16);
    v0 += __shfl_xor(v0, 32); v1 += __shfl_xor(v1, 32);
    if (lane == 0) {
      float2 o; o.x = v0 + bo0; o.y = v1 + bo1;
      *(float2*)(out + ((b0 + wave) * T_ + (T_ - 1)) * 2) = o;
    }
  }
}

extern "C" void kernel_launch(void* const* d_in, const int* in_sizes, int n_in,
                              void* d_out, int out_size, void* d_ws, size_t ws_size,
                              hipStream_t stream) {
  (void)in_sizes; (void)n_in; (void)out_size; (void)ws_size;
  const float* x   = (const float*)d_in[0];
  const float* h0  = (const float*)d_in[1];
  const float* Wa  = (const float*)d_in[2];
  const float* ba  = (const float*)d_in[3];
  const float* Wp1 = (const float*)d_in[4];
  const float* bp1 = (const float*)d_in[5];
  const float* Wp2 = (const float*)d_in[6];
  const float* bp2 = (const float*)d_in[7];
  const float* Wz  = (const float*)d_in[8];
  const float* bz  = (const float*)d_in[9];
  const float* Wh  = (const float*)d_in[10];
  const float* bh  = (const float*)d_in[11];
  const float* Wo  = (const float*)d_in[12];
  const float* bo  = (const float*)d_in[13];

  float* out = (float*)d_out;
  char*  ws  = (char*)d_ws;
  unsigned* u_ex = (unsigned*)ws;                 // 16 groups * 16KB = 256 KB
  unsigned* h_ex = (unsigned*)(ws + 262144);      // 256 KB

  // seqs restart at 1 every replay -> stale chunks from a previous replay
  // would carry valid-looking seqs. Zero both exchange regions each launch.
  hipMemsetAsync(ws, 0, 524288, stream);

  pgjanet_persist<<<dim3(GB * GC), dim3(NTHR), 0, stream>>>(
      x, h0, Wa, ba, Wp1, bp1, Wp2, bp2, Wz, bz, Wh, bh, Wo, bo,
      out, u_ex, h_ex);
}